// Round 1
// baseline (98.162 us; speedup 1.0000x reference)
//
#include <hip/hip_runtime.h>

#define N2 128
#define MM 16384
#define START 6
#define CB 32        // columns per block -> 512 blocks
#define BT 256       // 4 waves; 8 shares of 32 lanes; share g owns row-groups {g, 15-g}
#define FSTR 148     // fC col-major stride: mult of 4 (16B vectors); 148%32=20 -> uniform bank spread for b128
#define HSTR 20      // hrow col-major stride: mult of 4 (16B vectors); uniform bank spread

// Load a 24-float window from LDS as 6x ds_read_b128 (base must be 16B-aligned).
__device__ __forceinline__ void ldwin24(float* dst, const float* base) {
    const float4* p4 = reinterpret_cast<const float4*>(base);
#pragma unroll
    for (int e = 0; e < 6; ++e) {
        float4 q = p4[e];
        dst[4 * e + 0] = q.x; dst[4 * e + 1] = q.y;
        dst[4 * e + 2] = q.z; dst[4 * e + 3] = q.w;
    }
}

__global__ __launch_bounds__(BT, 2) void npi_fused(
    const float* __restrict__ rt, const float* __restrict__ dgt,
    const float* __restrict__ si, const float* __restrict__ f,
    const float* __restrict__ seed, float* __restrict__ out)
{
    __shared__ __align__(16) float fC[CB * FSTR];         // 18.5 KiB  [c][15+d], zero for d<0 and d<2
    __shared__ __align__(16) float hrow2[2 * CB * HSTR];  //  5.0 KiB  double-buffered, col-major [buf][c][k]
    __shared__ __align__(16) float si_sh[128];            // si_sh[j] = si[j+1]  (shift => 16B-aligned windows)
    __shared__ float lred[4];

    const int t = threadIdx.x;
    const int c = t & 31;
    const int g = t >> 5;          // share 0..7
    const int w = t >> 6;
    const int m = blockIdx.x * CB + c;

    // ---- global loads fired early (latency hidden under staging) ----
    float fregs[16];
#pragma unroll
    for (int q = 0; q < 16; ++q)
        fregs[q] = f[((g << 4) + q) * MM + m];
    float sd[START];
#pragma unroll
    for (int k = 0; k < START; ++k) sd[k] = seed[k * MM + m];
    float rtv[16];
#pragma unroll
    for (int k = 0; k < 16; ++k) rtv[k] = rt[k * MM + m];

    // ---- stage si (shifted by one so off-15 windows are 16B-aligned) ----
    if (t < 127) si_sh[t] = si[t + 1];
    if (t == 127) si_sh[127] = 0.f;
    // ---- stage f (col-major, zero-padded d<0 and d<2) ----
#pragma unroll
    for (int z = 0; z < 2; ++z) {
        int p = t + z * BT;
        if (p < 15 * CB) fC[(p & 31) * FSTR + (p >> 5)] = 0.f;  // idx 0..14 (d<0)
    }
#pragma unroll
    for (int q = 0; q < 16; ++q) {
        int d = (g << 4) + q;
        fC[c * FSTR + 15 + d] = (d < 2) ? 0.f : fregs[q];
    }
    __syncthreads();

    float sr[16];
#pragma unroll
    for (int k = 1; k < 16; ++k) sr[k] = si_sh[k - 1];   // = si[k]

    float Hacc[2][8], Eacc[2][8];
#pragma unroll
    for (int pass = 0; pass < 2; ++pass)
#pragma unroll
        for (int r = 0; r < 8; ++r) { Hacc[pass][r] = 0.f; Eacc[pass][r] = 0.f; }

    float v[16], rtn[16];

    // ================= chunk 0 =================
    {
        float p_[16];
#pragma unroll
        for (int k = 0; k < 16; ++k) p_[k] = 0.f;
#pragma unroll
        for (int k = 0; k < 16; ++k) {
            float vk;
            if (k < START) vk = sd[k];
            else vk = rtv[k] * (p_[k] + sr[1] * v[k - 1]);
            v[k] = vk;
#pragma unroll
            for (int k2 = k + 2; k2 < 16; ++k2)
                p_[k2] += sr[k2 - k] * vk;
        }
    }
#pragma unroll
    for (int k = 0; k < 16; ++k) rtn[k] = rt[(16 + k) * MM + m];  // prefetch
#pragma unroll
    for (int pass = 0; pass < 2; ++pass) {
        const int gi = pass ? (15 - g) : g;
        if (gi >= 2) {                         // H: strictly future rows
            float sw[24];                      // sw[e] = si[8gi-15+e]
            ldwin24(sw, &si_sh[(gi << 3) - 16]);
#pragma unroll
            for (int r = 0; r < 8; ++r)
#pragma unroll
                for (int k = 0; k < 16; ++k)
                    Hacc[pass][r] += v[k] * sw[15 + r - k];
        }
        {                                      // E: all groups (zero-pad handles d<2)
            float fw[24];
            ldwin24(fw, &fC[c * FSTR + (gi << 3)]);
#pragma unroll
            for (int r = 0; r < 8; ++r)
#pragma unroll
                for (int k = 0; k < 16; ++k)
                    Eacc[pass][r] += v[k] * fw[15 + r - k];
        }
    }
#pragma unroll
    for (int k = 0; k < 16; ++k) rtv[k] = rtn[k];

    // ================= chunks 1..7 (ONE barrier per chunk: hrow double-buffered) =================
    for (int cb = 1; cb < 8; ++cb) {
        float* hbuf = &hrow2[(cb & 1) * (CB * HSTR)];
        // owners publish this chunk's H (vectorized 2x b128)
#pragma unroll
        for (int pass = 0; pass < 2; ++pass) {
            const int gi = pass ? (15 - g) : g;
            if ((gi >> 1) == cb) {
                float4* hp = reinterpret_cast<float4*>(&hbuf[c * HSTR + ((gi & 1) << 3)]);
                hp[0] = make_float4(Hacc[pass][0], Hacc[pass][1], Hacc[pass][2], Hacc[pass][3]);
                hp[1] = make_float4(Hacc[pass][4], Hacc[pass][5], Hacc[pass][6], Hacc[pass][7]);
            }
        }
        __syncthreads();

        // triangle (redundant per lane; short dependence chain)
        float p_[16];
        {
            const float4* pp = reinterpret_cast<const float4*>(&hbuf[c * HSTR]);
#pragma unroll
            for (int e = 0; e < 4; ++e) {
                float4 q = pp[e];
                p_[4 * e + 0] = q.x; p_[4 * e + 1] = q.y;
                p_[4 * e + 2] = q.z; p_[4 * e + 3] = q.w;
            }
        }
#pragma unroll
        for (int k = 0; k < 16; ++k) {
            float vk = (k == 0) ? (rtv[0] * p_[0])
                                : (rtv[k] * (p_[k] + sr[1] * v[k - 1]));
            v[k] = vk;
#pragma unroll
            for (int k2 = k + 2; k2 < 16; ++k2)
                p_[k2] += sr[k2 - k] * vk;
        }
        if (cb < 7) {
#pragma unroll
            for (int k = 0; k < 16; ++k)
                rtn[k] = rt[(((cb + 1) << 4) + k) * MM + m];
        }

        // accumulate H/E contributions of this chunk into owned rows
#pragma unroll
        for (int pass = 0; pass < 2; ++pass) {
            const int gi = pass ? (15 - g) : g;
            if (gi >= 2 * cb + 2) {
                float sw[24];                  // sw[e] = si[8gi-16cb-15+e]
                ldwin24(sw, &si_sh[(gi << 3) - (cb << 4) - 16]);
#pragma unroll
                for (int r = 0; r < 8; ++r)
#pragma unroll
                    for (int k = 0; k < 16; ++k)
                        Hacc[pass][r] += v[k] * sw[15 + r - k];
            }
            if (gi >= 2 * cb) {
                float fw[24];
                ldwin24(fw, &fC[c * FSTR + (gi << 3) - (cb << 4)]);
#pragma unroll
                for (int r = 0; r < 8; ++r)
#pragma unroll
                    for (int k = 0; k < 16; ++k)
                        Eacc[pass][r] += v[k] * fw[15 + r - k];
            }
        }
#pragma unroll
        for (int k = 0; k < 16; ++k) rtv[k] = rtn[k];
        // no trailing barrier: next chunk publishes into the other hrow buffer
    }

    // ---- loss (dgt loaded here, not held across the main loop) ----
    float lsum = 0.f;
#pragma unroll
    for (int pass = 0; pass < 2; ++pass) {
        const int gi = pass ? (15 - g) : g;
#pragma unroll
        for (int r = 0; r < 8; ++r) {
            const int i = (gi << 3) + r;
            float e = Eacc[pass][r];
            if (i == 0) e = 1e-9f;
            else if (i < START) e = 0.f;
            float diff = e - dgt[i * MM + m];
            lsum += diff * diff;
        }
    }
#pragma unroll
    for (int off = 32; off > 0; off >>= 1)
        lsum += __shfl_down(lsum, off, 64);
    if ((t & 63) == 0) lred[w] = lsum;
    __syncthreads();
    if (t == 0)
        atomicAdd(out, (lred[0] + lred[1] + lred[2] + lred[3]) *
                       (1.0f / ((float)N2 * (float)MM)));
}

extern "C" void kernel_launch(void* const* d_in, const int* in_sizes, int n_in,
                              void* d_out, int out_size, void* d_ws, size_t ws_size,
                              hipStream_t stream) {
    const float* rt   = (const float*)d_in[0];
    const float* dgt  = (const float*)d_in[1];
    const float* si   = (const float*)d_in[2];
    const float* f    = (const float*)d_in[3];
    const float* seed = (const float*)d_in[4];

    hipMemsetAsync(d_out, 0, sizeof(float), stream);
    npi_fused<<<dim3(MM / CB), dim3(BT), 0, stream>>>(
        rt, dgt, si, f, seed, (float*)d_out);
}